// Round 26
// baseline (666.380 us; speedup 1.0000x reference)
//
#include <hip/hip_runtime.h>

#define EPS 1e-5f
#define PITCH 528   // bytes per LDS row (264 f16); 132 words % 32 banks = 4

typedef __attribute__((ext_vector_type(8))) _Float16 f16x8;
typedef __attribute__((ext_vector_type(4))) _Float16 f16x4v;
typedef __attribute__((ext_vector_type(2))) _Float16 f16x2v;
typedef __attribute__((ext_vector_type(16))) float f32x16;

// ---- prep: convert node features x (fp32) -> fp16 (25.6MB, L3-resident) ----
__global__ __launch_bounds__(256) void prep_x(const float* __restrict__ x,
                                              _Float16* __restrict__ x16, long n)
{
    const long i = ((long)blockIdx.x * 256 + threadIdx.x) * 8;
    if (i + 7 < n) {
        const float4 a = *reinterpret_cast<const float4*>(&x[i]);
        const float4 b = *reinterpret_cast<const float4*>(&x[i + 4]);
        f16x8 v;
        v[0] = (_Float16)a.x; v[1] = (_Float16)a.y; v[2] = (_Float16)a.z; v[3] = (_Float16)a.w;
        v[4] = (_Float16)b.x; v[5] = (_Float16)b.y; v[6] = (_Float16)b.z; v[7] = (_Float16)b.w;
        *reinterpret_cast<f16x8*>(&x16[i]) = v;
    }
}

// ---- prep: repack weights into fp16 32x32x16 MFMA A-fragments of W^T ----
// w1 (256x256): frag(ft 0..7, ks 0..15): lane l, elem j <- W1[ks*16+(l>>5)*8+j][ft*32+(l&31)]
// w2 (256x128): frag(ft2 0..3, ks 0..15): lane l, elem j <- W2[ks*16+(l>>5)*8+j][ft2*32+(l&31)]
__global__ __launch_bounds__(256) void prep_weights(
    const float* __restrict__ w1, const float* __restrict__ w2,
    _Float16* __restrict__ wb1, _Float16* __restrict__ wb2)
{
    const int t = blockIdx.x * 256 + threadIdx.x;
    const int lane = t & 63, frag = t >> 6;
    _Float16 v[8];
    if (frag < 128) {                 // w1: 8 ft x 16 ks
        const int row0 = (frag & 15) * 16 + (lane >> 5) * 8;
        const int col = (frag >> 4) * 32 + (lane & 31);
        #pragma unroll
        for (int j = 0; j < 8; ++j) v[j] = (_Float16)w1[(row0 + j) * 256 + col];
        *reinterpret_cast<f16x8*>(&wb1[frag * 512 + lane * 8]) = *reinterpret_cast<f16x8*>(v);
    } else if (frag < 192) {          // w2: 4 ft2 x 16 ks
        const int f = frag - 128;
        const int row0 = (f & 15) * 16 + (lane >> 5) * 8;
        const int col = (f >> 4) * 32 + (lane & 31);
        #pragma unroll
        for (int j = 0; j < 8; ++j) v[j] = (_Float16)w2[(row0 + j) * 128 + col];
        *reinterpret_cast<f16x8*>(&wb2[f * 512 + lane * 8]) = *reinterpret_cast<f16x8*>(v);
    }
}

// ---- fused MLP: 256 edges/block, 1024 thr (16 waves), plain-fp16 1-MFMA GEMMs ----
// 256-edge tiles halve per-edge block overhead + weight-L2 traffic vs R21 (128).
// HARD CONSTRAINT (R2-R16): LDS > 80KB -> ONE resident block/CU (2 blocks/CU
// corrupts ~0.04 regardless of numerics). LDS = 135+16+8 = 159.7KB (natural).
// STRAIGHT-LINE single-tile body (hipcc spills any loop-carrying structure at
// 1024 thr and caps VGPR at 128 even at 512 thr -- R17/R18/R22/R23/R24).
template<bool X16>
__global__ __launch_bounds__(1024, 4) void edge_mlp(
    const float* __restrict__ x, const _Float16* __restrict__ x16,
    const int* __restrict__ ei,
    const float* __restrict__ ln0_g, const float* __restrict__ ln0_b,
    const _Float16* __restrict__ wb1, const float* __restrict__ b1,
    const float* __restrict__ ln1_g, const float* __restrict__ ln1_b,
    const _Float16* __restrict__ wb2, const float* __restrict__ b2,
    const float* __restrict__ ln2_g, const float* __restrict__ ln2_b,
    const float* __restrict__ wp, const float* __restrict__ bp,
    const float* __restrict__ ww, const float* __restrict__ bw,
    float* __restrict__ out, int E)
{
    __shared__ __align__(16) _Float16 hh[256 * 264];   // 135KB: h0 then h1 (overlay)
    __shared__ __align__(8) float red[16][128][2];     // 16KB
    __shared__ __align__(8) float red2[16][64][2];     // 8KB  (total 159.7KB)

    const int tid = threadIdx.x, lane = tid & 63, w = tid >> 6;   // w in 0..15
    const int l31 = lane & 31, lh = lane >> 5;
    const int ft = w >> 1, ep = w & 1;       // GEMM1: feats ft*32..+32, edges ep*128..+128
    const int ft2 = w >> 2, eq = w & 3;      // GEMM2: feats ft2*32..+32, tiles 2eq,2eq+1
    const long base = (long)blockIdx.x * 256;

    // ---------- P1: wave-local sidx + gather + LN0 -> h0 (wave w: edges w*16..+16) ----------
    {
        int si = 0;
        if (lane < 32) {
            const long idx = base + w * 16 + (lane >> 1);
            const int s = lane & 1;
            si = (idx < E) ? ei[(long)s * E + idx] : 0;
        }
        const int c = 2 * lane;
        const float ga = ln0_g[c], gb = ln0_g[c + 1], gc = ln0_g[128 + c], gd = ln0_g[129 + c];
        const float ba = ln0_b[c], bb = ln0_b[c + 1], bc = ln0_b[128 + c], bd = ln0_b[129 + c];
        char* hhc = (char*)hh;
        #pragma unroll
        for (int e8 = 0; e8 < 16; ++e8) {
            const int s0 = __shfl(si, e8 * 2 + 0);
            const int s1 = __shfl(si, e8 * 2 + 1);
            const int e = w * 16 + e8;
            float2 sv, dv;
            if constexpr (X16) {
                const f16x2v a2 = *reinterpret_cast<const f16x2v*>(&x16[(long)s0 * 128 + c]);
                const f16x2v d2 = *reinterpret_cast<const f16x2v*>(&x16[(long)s1 * 128 + c]);
                sv.x = (float)a2[0]; sv.y = (float)a2[1];
                dv.x = (float)d2[0]; dv.y = (float)d2[1];
            } else {
                sv = *reinterpret_cast<const float2*>(&x[(long)s0 * 128 + c]);
                dv = *reinterpret_cast<const float2*>(&x[(long)s1 * 128 + c]);
            }
            const float a0 = sv.x + dv.x, a1 = sv.y + dv.y;
            const float m0 = sv.x * dv.x, m1 = sv.y * dv.y;
            float s = a0 + a1 + m0 + m1;
            float q = a0 * a0 + a1 * a1 + m0 * m0 + m1 * m1;
            #pragma unroll
            for (int o = 32; o; o >>= 1) { s += __shfl_xor(s, o); q += __shfl_xor(q, o); }
            const float mu = s * (1.f / 256.f);
            const float rs = rsqrtf(q * (1.f / 256.f) - mu * mu + EPS);
            f16x2v p0, p1;
            p0[0] = (_Float16)((a0 - mu) * rs * ga + ba);
            p0[1] = (_Float16)((a1 - mu) * rs * gb + bb);
            p1[0] = (_Float16)((m0 - mu) * rs * gc + bc);
            p1[1] = (_Float16)((m1 - mu) * rs * gd + bd);
            const int o0 = e * PITCH + 4 * lane;
            const int o1 = e * PITCH + 256 + 4 * lane;
            *reinterpret_cast<f16x2v*>(hhc + o0) = p0;
            *reinterpret_cast<f16x2v*>(hhc + o1) = p1;
        }
    }
    __syncthreads();   // [1]

    // ---------- B0: GEMM1 32x32x16 fp16 (4 edge-tiles) + bias + LN1 stats partial ----------
    f32x16 acc1[4] = {};
    {
        const char* hhc = (const char*)hh;
        int boff[4];
        #pragma unroll
        for (int t = 0; t < 4; ++t) boff[t] = (ep * 128 + t * 32 + l31) * PITCH + lh * 16;
        for (int ks = 0; ks < 16; ++ks) {
            const f16x8 a = *reinterpret_cast<const f16x8*>(&wb1[(ft * 16 + ks) * 512 + lane * 8]);
            #pragma unroll
            for (int t = 0; t < 4; ++t) {
                const f16x8 b = *reinterpret_cast<const f16x8*>(hhc + boff[t] + ks * 32);
                acc1[t] = __builtin_amdgcn_mfma_f32_32x32x16_f16(a, b, acc1[t], 0, 0, 0);
            }
        }
        float bi[4][4];
        #pragma unroll
        for (int g2 = 0; g2 < 4; ++g2)
            *reinterpret_cast<float4*>(bi[g2]) =
                *reinterpret_cast<const float4*>(&b1[ft * 32 + g2 * 8 + 4 * lh]);
        #pragma unroll
        for (int t = 0; t < 4; ++t) {
            float s = 0.f, q = 0.f;
            #pragma unroll
            for (int r = 0; r < 16; ++r) {
                const float v2 = acc1[t][r] + bi[r >> 2][r & 3];
                acc1[t][r] = v2; s += v2; q += v2 * v2;
            }
            s += __shfl_xor(s, 32); q += __shfl_xor(q, 32);
            if (lane < 32) { red[w][t * 32 + lane][0] = s; red[w][t * 32 + lane][1] = q; }
        }
    }
    __syncthreads();   // [2]

    // ---------- B1: per-lane LN1 finalize + apply + relu -> h1 (overlays h0) ----------
    {
        char* hhc = (char*)hh;
        #pragma unroll
        for (int t = 0; t < 4; ++t) {
            const int el = t * 32 + l31;              // edge within ep-half (0..127)
            const int e1 = ep * 128 + el;             // tile edge idx
            float S = 0.f, Q = 0.f;
            #pragma unroll
            for (int f = 0; f < 8; ++f) { S += red[2 * f + ep][el][0]; Q += red[2 * f + ep][el][1]; }
            const float mu = S * (1.f / 256.f);
            const float rs = rsqrtf(Q * (1.f / 256.f) - mu * mu + EPS);
            #pragma unroll
            for (int g2 = 0; g2 < 4; ++g2) {
                const int f0 = ft * 32 + g2 * 8 + 4 * lh;
                float gv[4], bv[4];
                *reinterpret_cast<float4*>(gv) = *reinterpret_cast<const float4*>(&ln1_g[f0]);
                *reinterpret_cast<float4*>(bv) = *reinterpret_cast<const float4*>(&ln1_b[f0]);
                f16x4v pk;
                #pragma unroll
                for (int ii = 0; ii < 4; ++ii)
                    pk[ii] = (_Float16)fmaxf((acc1[t][g2 * 4 + ii] - mu) * rs * gv[ii] + bv[ii], 0.f);
                *reinterpret_cast<f16x4v*>(hhc + e1 * PITCH + f0 * 2) = pk;
            }
        }
    }
    __syncthreads();   // [3]

    // ---------- B2: GEMM2 32x32x16 fp16 (2 edge-tiles) + bias + LN2 stats partial ----------
    f32x16 acc2[2] = {};
    {
        const char* hhc = (const char*)hh;
        int boff2[2];
        #pragma unroll
        for (int ntl = 0; ntl < 2; ++ntl)
            boff2[ntl] = ((2 * eq + ntl) * 32 + l31) * PITCH + lh * 16;
        for (int ks = 0; ks < 16; ++ks) {
            const f16x8 a = *reinterpret_cast<const f16x8*>(&wb2[(ft2 * 16 + ks) * 512 + lane * 8]);
            #pragma unroll
            for (int ntl = 0; ntl < 2; ++ntl) {
                const f16x8 b = *reinterpret_cast<const f16x8*>(hhc + boff2[ntl] + ks * 32);
                acc2[ntl] = __builtin_amdgcn_mfma_f32_32x32x16_f16(a, b, acc2[ntl], 0, 0, 0);
            }
        }
        float bi[4][4];
        #pragma unroll
        for (int g2 = 0; g2 < 4; ++g2)
            *reinterpret_cast<float4*>(bi[g2]) =
                *reinterpret_cast<const float4*>(&b2[ft2 * 32 + g2 * 8 + 4 * lh]);
        #pragma unroll
        for (int ntl = 0; ntl < 2; ++ntl) {
            float s = 0.f, q = 0.f;
            #pragma unroll
            for (int r = 0; r < 16; ++r) {
                const float v2 = acc2[ntl][r] + bi[r >> 2][r & 3];
                acc2[ntl][r] = v2; s += v2; q += v2 * v2;
            }
            s += __shfl_xor(s, 32); q += __shfl_xor(q, 32);
            if (lane < 32) { red[w][ntl * 32 + lane][0] = s; red[w][ntl * 32 + lane][1] = q; }
        }
    }
    __syncthreads();   // [4]

    // ---------- B3: per-lane LN2 finalize + apply + heads partial -> red2 ----------
    {
        #pragma unroll
        for (int ntl = 0; ntl < 2; ++ntl) {
            float S = 0.f, Q = 0.f;
            #pragma unroll
            for (int f2 = 0; f2 < 4; ++f2) {
                S += red[f2 * 4 + eq][ntl * 32 + l31][0];
                Q += red[f2 * 4 + eq][ntl * 32 + l31][1];
            }
            const float mu = S * (1.f / 128.f);
            const float rs = rsqrtf(Q * (1.f / 128.f) - mu * mu + EPS);
            float pp = 0.f, ws2 = 0.f;
            #pragma unroll
            for (int g2 = 0; g2 < 4; ++g2) {
                const int f0 = ft2 * 32 + g2 * 8 + 4 * lh;
                float gv[4], bv[4], pv[4], wv[4];
                *reinterpret_cast<float4*>(gv) = *reinterpret_cast<const float4*>(&ln2_g[f0]);
                *reinterpret_cast<float4*>(bv) = *reinterpret_cast<const float4*>(&ln2_b[f0]);
                *reinterpret_cast<float4*>(pv) = *reinterpret_cast<const float4*>(&wp[f0]);
                *reinterpret_cast<float4*>(wv) = *reinterpret_cast<const float4*>(&ww[f0]);
                #pragma unroll
                for (int ii = 0; ii < 4; ++ii) {
                    const float t = fmaxf((acc2[ntl][g2 * 4 + ii] - mu) * rs * gv[ii] + bv[ii], 0.f);
                    pp += t * pv[ii]; ws2 += t * wv[ii];
                }
            }
            pp += __shfl_xor(pp, 32); ws2 += __shfl_xor(ws2, 32);
            if (lane < 32) { red2[w][ntl * 32 + l31][0] = pp; red2[w][ntl * 32 + l31][1] = ws2; }
        }
    }
    __syncthreads();   // [5]

    // ---------- B4: output (edges 0..255) ----------
    if (tid < 256 && base + tid < E) {
        const int tile = tid >> 5, l = tid & 31;
        const int eqo = tile >> 1, ntl = tile & 1;
        float P = bp[0], W = bw[0];
        #pragma unroll
        for (int f2 = 0; f2 < 4; ++f2) {
            P += red2[f2 * 4 + eqo][ntl * 32 + l][0];
            W += red2[f2 * 4 + eqo][ntl * 32 + l][1];
        }
        out[base + tid] = P;                         // logits
        out[(long)E + base + tid] = fmaxf(W, 0.f);   // relu'd weights
    }
}

extern "C" void kernel_launch(void* const* d_in, const int* in_sizes, int n_in,
                              void* d_out, int out_size, void* d_ws, size_t ws_size,
                              hipStream_t stream) {
    const float* x     = (const float*)d_in[0];
    const int*   ei    = (const int*)  d_in[1];
    const float* ln0_g = (const float*)d_in[2];
    const float* ln0_b = (const float*)d_in[3];
    const float* w1    = (const float*)d_in[4];
    const float* b1    = (const float*)d_in[5];
    const float* ln1_g = (const float*)d_in[6];
    const float* ln1_b = (const float*)d_in[7];
    const float* w2    = (const float*)d_in[8];
    const float* b2    = (const float*)d_in[9];
    const float* ln2_g = (const float*)d_in[10];
    const float* ln2_b = (const float*)d_in[11];
    const float* wp    = (const float*)d_in[12];
    const float* bp    = (const float*)d_in[13];
    const float* ww    = (const float*)d_in[14];
    const float* bw    = (const float*)d_in[15];

    _Float16* wb1 = (_Float16*)d_ws;        // 128 frags * 512 = 128KB
    _Float16* wb2 = wb1 + 128 * 512;        // 64 frags * 512 = 64KB
    _Float16* x16 = wb2 + 64 * 512;         // node features in fp16

    const int E = in_sizes[1] / 2;
    const long xN = (long)in_sizes[0];      // N*D elements
    const size_t need = 192 * 1024 + (size_t)xN * sizeof(_Float16);

    prep_weights<<<48, 256, 0, stream>>>(w1, w2, wb1, wb2);
    if (ws_size >= need) {
        const int nb = (int)((xN / 8 + 255) / 256);
        prep_x<<<nb, 256, 0, stream>>>(x, x16, xN);
        edge_mlp<true><<<(E + 255) / 256, 1024, 0, stream>>>(
            x, x16, ei, ln0_g, ln0_b, wb1, b1, ln1_g, ln1_b, wb2, b2,
            ln2_g, ln2_b, wp, bp, ww, bw, (float*)d_out, E);
    } else {
        edge_mlp<false><<<(E + 255) / 256, 1024, 0, stream>>>(
            x, x16, ei, ln0_g, ln0_b, wb1, b1, ln1_g, ln1_b, wb2, b2,
            ln2_g, ln2_b, wp, bp, ww, bw, (float*)d_out, E);
    }
}

// Round 27
// 575.833 us; speedup vs baseline: 1.1572x; 1.1572x over previous
//
#include <hip/hip_runtime.h>

#define EPS 1e-5f
#define PITCH 528   // bytes per LDS row (264 f16); 132 words % 32 banks = 4

typedef __attribute__((ext_vector_type(8))) _Float16 f16x8;
typedef __attribute__((ext_vector_type(4))) _Float16 f16x4v;
typedef __attribute__((ext_vector_type(2))) _Float16 f16x2v;
typedef __attribute__((ext_vector_type(16))) float f32x16;

// ---- prep: convert node features x (fp32) -> fp16 (25.6MB, L3-resident) ----
__global__ __launch_bounds__(256) void prep_x(const float* __restrict__ x,
                                              _Float16* __restrict__ x16, long n)
{
    const long i = ((long)blockIdx.x * 256 + threadIdx.x) * 8;
    if (i + 7 < n) {
        const float4 a = *reinterpret_cast<const float4*>(&x[i]);
        const float4 b = *reinterpret_cast<const float4*>(&x[i + 4]);
        f16x8 v;
        v[0] = (_Float16)a.x; v[1] = (_Float16)a.y; v[2] = (_Float16)a.z; v[3] = (_Float16)a.w;
        v[4] = (_Float16)b.x; v[5] = (_Float16)b.y; v[6] = (_Float16)b.z; v[7] = (_Float16)b.w;
        *reinterpret_cast<f16x8*>(&x16[i]) = v;
    }
}

// ---- prep: repack weights into fp16 32x32x16 MFMA A-fragments of W^T ----
// w1 (256x256): frag(ft 0..7, ks 0..15): lane l, elem j <- W1[ks*16+(l>>5)*8+j][ft*32+(l&31)]
// w2 (256x128): frag(ft2 0..3, ks 0..15): lane l, elem j <- W2[ks*16+(l>>5)*8+j][ft2*32+(l&31)]
__global__ __launch_bounds__(256) void prep_weights(
    const float* __restrict__ w1, const float* __restrict__ w2,
    _Float16* __restrict__ wb1, _Float16* __restrict__ wb2)
{
    const int t = blockIdx.x * 256 + threadIdx.x;
    const int lane = t & 63, frag = t >> 6;
    _Float16 v[8];
    if (frag < 128) {                 // w1: 8 ft x 16 ks
        const int row0 = (frag & 15) * 16 + (lane >> 5) * 8;
        const int col = (frag >> 4) * 32 + (lane & 31);
        #pragma unroll
        for (int j = 0; j < 8; ++j) v[j] = (_Float16)w1[(row0 + j) * 256 + col];
        *reinterpret_cast<f16x8*>(&wb1[frag * 512 + lane * 8]) = *reinterpret_cast<f16x8*>(v);
    } else if (frag < 192) {          // w2: 4 ft2 x 16 ks
        const int f = frag - 128;
        const int row0 = (f & 15) * 16 + (lane >> 5) * 8;
        const int col = (f >> 4) * 32 + (lane & 31);
        #pragma unroll
        for (int j = 0; j < 8; ++j) v[j] = (_Float16)w2[(row0 + j) * 128 + col];
        *reinterpret_cast<f16x8*>(&wb2[f * 512 + lane * 8]) = *reinterpret_cast<f16x8*>(v);
    }
}

// ---- fused MLP: 128 edges/block, 1024 thr (16 waves), plain-fp16 1-MFMA GEMMs ----
// X16: gather from pre-converted fp16 x (footprint 25.6MB -> L3-resident).
// HARD CONSTRAINT (R2-R16): LDS > 80KB -> ONE resident block/CU (2 blocks/CU
// corrupts ~0.04 regardless of numerics). hh carries +16KB pad -> 96KB.
// STRAIGHT-LINE single-tile body: hipcc spills ANY loop-carrying structure at
// 1024 thr (R17/R18/R22), caps VGPR at 128 even at 512 thr (R23/R24), and
// spills >2 live f32x16 accumulators (R26: 256-edge tile) -- this shape is
// the only clean-compiling point in the explored design space.
template<bool X16>
__global__ __launch_bounds__(1024, 4) void edge_mlp(
    const float* __restrict__ x, const _Float16* __restrict__ x16,
    const int* __restrict__ ei,
    const float* __restrict__ ln0_g, const float* __restrict__ ln0_b,
    const _Float16* __restrict__ wb1, const float* __restrict__ b1,
    const float* __restrict__ ln1_g, const float* __restrict__ ln1_b,
    const _Float16* __restrict__ wb2, const float* __restrict__ b2,
    const float* __restrict__ ln2_g, const float* __restrict__ ln2_b,
    const float* __restrict__ wp, const float* __restrict__ bp,
    const float* __restrict__ ww, const float* __restrict__ bw,
    float* __restrict__ out, int E)
{
    __shared__ __align__(16) _Float16 hh[128 * 264 + 8192];  // 67.6KB + 16KB pad
    __shared__ __align__(8) float red[16][64][2];   // 8KB
    __shared__ __align__(8) float red2[16][32][2];  // 4KB  (total ~96KB)

    const int tid = threadIdx.x, lane = tid & 63, w = tid >> 6;   // w in 0..15
    const int l31 = lane & 31, lh = lane >> 5;
    const int ft = w >> 1, ep = w & 1;       // GEMM1: feats ft*32..+32, edges ep*64..+64
    const int ft2 = w >> 2, et2 = w & 3;     // GEMM2: feats ft2*32..+32, edges et2*32..+32
    const long base = (long)blockIdx.x * 128;

    // ---------- P1: wave-local sidx + gather + LN0 -> h0 (fp16, single plane) ----------
    {
        int si = 0;
        if (lane < 16) {
            const long idx = base + w * 8 + (lane >> 1);
            const int s = lane & 1;
            si = (idx < E) ? ei[(long)s * E + idx] : 0;
        }
        const int c = 2 * lane;
        const float ga = ln0_g[c], gb = ln0_g[c + 1], gc = ln0_g[128 + c], gd = ln0_g[129 + c];
        const float ba = ln0_b[c], bb = ln0_b[c + 1], bc = ln0_b[128 + c], bd = ln0_b[129 + c];
        char* hhc = (char*)hh;
        #pragma unroll
        for (int e8 = 0; e8 < 8; ++e8) {
            const int s0 = __shfl(si, e8 * 2 + 0);
            const int s1 = __shfl(si, e8 * 2 + 1);
            const int e = w * 8 + e8;
            float2 sv, dv;
            if constexpr (X16) {
                const f16x2v a2 = *reinterpret_cast<const f16x2v*>(&x16[(long)s0 * 128 + c]);
                const f16x2v d2 = *reinterpret_cast<const f16x2v*>(&x16[(long)s1 * 128 + c]);
                sv.x = (float)a2[0]; sv.y = (float)a2[1];
                dv.x = (float)d2[0]; dv.y = (float)d2[1];
            } else {
                sv = *reinterpret_cast<const float2*>(&x[(long)s0 * 128 + c]);
                dv = *reinterpret_cast<const float2*>(&x[(long)s1 * 128 + c]);
            }
            const float a0 = sv.x + dv.x, a1 = sv.y + dv.y;
            const float m0 = sv.x * dv.x, m1 = sv.y * dv.y;
            float s = a0 + a1 + m0 + m1;
            float q = a0 * a0 + a1 * a1 + m0 * m0 + m1 * m1;
            #pragma unroll
            for (int o = 32; o; o >>= 1) { s += __shfl_xor(s, o); q += __shfl_xor(q, o); }
            const float mu = s * (1.f / 256.f);
            const float rs = rsqrtf(q * (1.f / 256.f) - mu * mu + EPS);
            f16x2v p0, p1;
            p0[0] = (_Float16)((a0 - mu) * rs * ga + ba);
            p0[1] = (_Float16)((a1 - mu) * rs * gb + bb);
            p1[0] = (_Float16)((m0 - mu) * rs * gc + bc);
            p1[1] = (_Float16)((m1 - mu) * rs * gd + bd);
            const int o0 = e * PITCH + 4 * lane;
            const int o1 = e * PITCH + 256 + 4 * lane;
            *reinterpret_cast<f16x2v*>(hhc + o0) = p0;
            *reinterpret_cast<f16x2v*>(hhc + o1) = p1;
        }
    }
    __syncthreads();   // [1]

    // ---------- B0: GEMM1 32x32x16 fp16 (reads h0) + bias + LN1 stats partial ----------
    f32x16 acc1[2] = {};
    {
        const char* hhc = (const char*)hh;
        const int boffA = (ep * 64 + l31) * PITCH + lh * 16;
        const int boffB = (ep * 64 + 32 + l31) * PITCH + lh * 16;
        for (int ks = 0; ks < 16; ++ks) {
            const f16x8 a = *reinterpret_cast<const f16x8*>(&wb1[(ft * 16 + ks) * 512 + lane * 8]);
            const f16x8 bA = *reinterpret_cast<const f16x8*>(hhc + boffA + ks * 32);
            acc1[0] = __builtin_amdgcn_mfma_f32_32x32x16_f16(a, bA, acc1[0], 0, 0, 0);
            const f16x8 bB = *reinterpret_cast<const f16x8*>(hhc + boffB + ks * 32);
            acc1[1] = __builtin_amdgcn_mfma_f32_32x32x16_f16(a, bB, acc1[1], 0, 0, 0);
        }
        float bi[4][4];
        #pragma unroll
        for (int g2 = 0; g2 < 4; ++g2)
            *reinterpret_cast<float4*>(bi[g2]) =
                *reinterpret_cast<const float4*>(&b1[ft * 32 + g2 * 8 + 4 * lh]);
        #pragma unroll
        for (int t = 0; t < 2; ++t) {
            float s = 0.f, q = 0.f;
            #pragma unroll
            for (int r = 0; r < 16; ++r) {
                const float v2 = acc1[t][r] + bi[r >> 2][r & 3];
                acc1[t][r] = v2; s += v2; q += v2 * v2;
            }
            s += __shfl_xor(s, 32); q += __shfl_xor(q, 32);
            if (lane < 32) { red[w][t * 32 + lane][0] = s; red[w][t * 32 + lane][1] = q; }
        }
    }
    __syncthreads();   // [2]

    // ---------- B1: per-lane LN1 finalize + apply + relu -> h1 (overlays h0) ----------
    {
        char* hhc = (char*)hh;
        #pragma unroll
        for (int t = 0; t < 2; ++t) {
            const int el = t * 32 + l31;
            const int e1 = ep * 64 + el;
            float S = 0.f, Q = 0.f;
            #pragma unroll
            for (int f = 0; f < 8; ++f) { S += red[2 * f + ep][el][0]; Q += red[2 * f + ep][el][1]; }
            const float mu = S * (1.f / 256.f);
            const float rs = rsqrtf(Q * (1.f / 256.f) - mu * mu + EPS);
            #pragma unroll
            for (int g2 = 0; g2 < 4; ++g2) {
                const int f0 = ft * 32 + g2 * 8 + 4 * lh;
                float gv[4], bv[4];
                *reinterpret_cast<float4*>(gv) = *reinterpret_cast<const float4*>(&ln1_g[f0]);
                *reinterpret_cast<float4*>(bv) = *reinterpret_cast<const float4*>(&ln1_b[f0]);
                f16x4v pk;
                #pragma unroll
                for (int ii = 0; ii < 4; ++ii)
                    pk[ii] = (_Float16)fmaxf((acc1[t][g2 * 4 + ii] - mu) * rs * gv[ii] + bv[ii], 0.f);
                *reinterpret_cast<f16x4v*>(hhc + e1 * PITCH + f0 * 2) = pk;
            }
        }
    }
    __syncthreads();   // [3]

    // ---------- B2: GEMM2 32x32x16 fp16 (reads h1) + bias + LN2 stats partial ----------
    f32x16 acc2 = {};
    {
        const char* hhc = (const char*)hh;
        const int e2 = et2 * 32 + l31;
        const int boff2 = e2 * PITCH + lh * 16;
        for (int ks = 0; ks < 16; ++ks) {
            const f16x8 a = *reinterpret_cast<const f16x8*>(&wb2[(ft2 * 16 + ks) * 512 + lane * 8]);
            const f16x8 b = *reinterpret_cast<const f16x8*>(hhc + boff2 + ks * 32);
            acc2 = __builtin_amdgcn_mfma_f32_32x32x16_f16(a, b, acc2, 0, 0, 0);
        }
        float bi[4][4];
        #pragma unroll
        for (int g2 = 0; g2 < 4; ++g2)
            *reinterpret_cast<float4*>(bi[g2]) =
                *reinterpret_cast<const float4*>(&b2[ft2 * 32 + g2 * 8 + 4 * lh]);
        float s = 0.f, q = 0.f;
        #pragma unroll
        for (int r = 0; r < 16; ++r) {
            const float v2 = acc2[r] + bi[r >> 2][r & 3];
            acc2[r] = v2; s += v2; q += v2 * v2;
        }
        s += __shfl_xor(s, 32); q += __shfl_xor(q, 32);
        if (lane < 32) { red[w][lane][0] = s; red[w][lane][1] = q; }
    }
    __syncthreads();   // [4]

    // ---------- B3: per-lane LN2 finalize + apply + heads partial -> red2 ----------
    {
        float S = 0.f, Q = 0.f;
        #pragma unroll
        for (int f2 = 0; f2 < 4; ++f2) { S += red[4 * f2 + et2][l31][0]; Q += red[4 * f2 + et2][l31][1]; }
        const float mu = S * (1.f / 128.f);
        const float rs = rsqrtf(Q * (1.f / 128.f) - mu * mu + EPS);
        float pp = 0.f, ws2 = 0.f;
        #pragma unroll
        for (int g2 = 0; g2 < 4; ++g2) {
            const int f0 = ft2 * 32 + g2 * 8 + 4 * lh;
            float gv[4], bv[4], pv[4], wv[4];
            *reinterpret_cast<float4*>(gv) = *reinterpret_cast<const float4*>(&ln2_g[f0]);
            *reinterpret_cast<float4*>(bv) = *reinterpret_cast<const float4*>(&ln2_b[f0]);
            *reinterpret_cast<float4*>(pv) = *reinterpret_cast<const float4*>(&wp[f0]);
            *reinterpret_cast<float4*>(wv) = *reinterpret_cast<const float4*>(&ww[f0]);
            #pragma unroll
            for (int ii = 0; ii < 4; ++ii) {
                const float t = fmaxf((acc2[g2 * 4 + ii] - mu) * rs * gv[ii] + bv[ii], 0.f);
                pp += t * pv[ii]; ws2 += t * wv[ii];
            }
        }
        pp += __shfl_xor(pp, 32); ws2 += __shfl_xor(ws2, 32);
        if (lane < 32) { red2[w][lane][0] = pp; red2[w][lane][1] = ws2; }
    }
    __syncthreads();   // [5]

    // ---------- B4: output ----------
    if (tid < 128 && base + tid < E) {
        const int q5 = tid >> 5, l = tid & 31;
        float P = bp[0], W = bw[0];
        #pragma unroll
        for (int f2 = 0; f2 < 4; ++f2) { P += red2[4 * f2 + q5][l][0]; W += red2[4 * f2 + q5][l][1]; }
        out[base + tid] = P;                         // logits
        out[(long)E + base + tid] = fmaxf(W, 0.f);   // relu'd weights
    }
}

extern "C" void kernel_launch(void* const* d_in, const int* in_sizes, int n_in,
                              void* d_out, int out_size, void* d_ws, size_t ws_size,
                              hipStream_t stream) {
    const float* x     = (const float*)d_in[0];
    const int*   ei    = (const int*)  d_in[1];
    const float* ln0_g = (const float*)d_in[2];
    const float* ln0_b = (const float*)d_in[3];
    const float* w1    = (const float*)d_in[4];
    const float* b1    = (const float*)d_in[5];
    const float* ln1_g = (const float*)d_in[6];
    const float* ln1_b = (const float*)d_in[7];
    const float* w2    = (const float*)d_in[8];
    const float* b2    = (const float*)d_in[9];
    const float* ln2_g = (const float*)d_in[10];
    const float* ln2_b = (const float*)d_in[11];
    const float* wp    = (const float*)d_in[12];
    const float* bp    = (const float*)d_in[13];
    const float* ww    = (const float*)d_in[14];
    const float* bw    = (const float*)d_in[15];

    _Float16* wb1 = (_Float16*)d_ws;        // 128 frags * 512 = 128KB
    _Float16* wb2 = wb1 + 128 * 512;        // 64 frags * 512 = 64KB
    _Float16* x16 = wb2 + 64 * 512;         // node features in fp16

    const int E = in_sizes[1] / 2;
    const long xN = (long)in_sizes[0];      // N*D elements
    const size_t need = 192 * 1024 + (size_t)xN * sizeof(_Float16);

    prep_weights<<<48, 256, 0, stream>>>(w1, w2, wb1, wb2);
    if (ws_size >= need) {
        const int nb = (int)((xN / 8 + 255) / 256);
        prep_x<<<nb, 256, 0, stream>>>(x, x16, xN);
        edge_mlp<true><<<(E + 127) / 128, 1024, 0, stream>>>(
            x, x16, ei, ln0_g, ln0_b, wb1, b1, ln1_g, ln1_b, wb2, b2,
            ln2_g, ln2_b, wp, bp, ww, bw, (float*)d_out, E);
    } else {
        edge_mlp<false><<<(E + 127) / 128, 1024, 0, stream>>>(
            x, x16, ei, ln0_g, ln0_b, wb1, b1, ln1_g, ln1_b, wb2, b2,
            ln2_g, ln2_b, wp, bp, ww, bw, (float*)d_out, E);
    }
}